// Round 1
// 235.571 us; speedup vs baseline: 1.0400x; 1.0400x over previous
//
#include <hip/hip_runtime.h>

// Edge-index generation for a B×H×W grid graph — LDS-staged, coalesced-flush rev.
//
// Ordering (matches the torch reference exactly):
//   per node i: [i,i], (i,left),(left,i) if x>0, (i,right),(right,i) if x<W-1,
//               (i,up),(up,i) if y>0, (i,down),(down,i) if y<H-1
//   then for the LAST node only: (i,sidx),(sidx,i) appended at the end
//   (loop-variable leak in the original torch code).
// Output layout: out[0..E) = row 0 (sources), out[E..2E) = row 1 (targets).
//
// Closed-form prefix sums (no scan):
//   count(x,y)   = 1 + 2([x>0]+[x<W-1]+[y>0]+[y<H-1])
//   perBatch     = HW + 4H(W-1) + 4W(H-1)
//   rowsPrefix(y)= y*(3W + 4(W-1)) + 2W*max(y-1,0)
//   sumRow(x,y)  = x*(1+2*ry) + 2*(max(x-1,0) + x),  ry=[y>0]+[y<H-1]
//
// This rev: o(i) is an exact prefix sum of per-node edge counts, so 256
// consecutive nodes own ONE contiguous output range (≤ 256*9 = 2304 ints per
// row). The previous rev's per-thread scattered 4B stores made every wave
// store instruction span ~36 distinct 64B segments (TA serialization). Here
// each block stages its span in LDS (2 × 9 KiB) and flushes with fully
// coalesced stores: lane t writes out[base+t], 256 B per wave per instruction.
// 18 KiB LDS + 256 threads → 8 blocks/CU (full 2048-thread occupancy).

__device__ __forceinline__ unsigned int node_off(
        unsigned int i, unsigned int HW, unsigned int W, unsigned int H,
        unsigned int perBatch) {
    const unsigned int b = i / HW;
    const unsigned int p = i - b * HW;
    const unsigned int y = p / W;
    const unsigned int x = p - y * W;
    const unsigned int ry = (y > 0) + (y < H - 1);
    const unsigned int rowsPrefix =
        y * (3u * W + 4u * (W - 1)) + 2u * W * (y > 0 ? y - 1 : 0);
    const unsigned int sumRow =
        x * (1u + 2u * ry) + 2u * ((x > 0 ? x - 1 : 0) + x);
    return b * perBatch + rowsPrefix + sumRow;
}

__device__ __forceinline__ unsigned int node_cnt(
        unsigned int i, unsigned int HW, unsigned int W, unsigned int H) {
    const unsigned int b = i / HW;
    const unsigned int p = i - b * HW;
    const unsigned int y = p / W;
    const unsigned int x = p - y * W;
    return 1u + 2u * ((x > 0) + (x < W - 1) + (y > 0) + (y < H - 1));
}

__global__ void __launch_bounds__(256)
EdgeIndexGenerator_12524124635757_kernel(
        const int* __restrict__ hptr, const int* __restrict__ wptr,
        int* __restrict__ out, unsigned int outSize) {
    const unsigned int H = (unsigned int)*hptr;
    const unsigned int W = (unsigned int)*wptr;
    const unsigned int E = outSize >> 1;
    const unsigned int HW = H * W;
    const unsigned int perBatch = HW + 4u * H * (W - 1) + 4u * W * (H - 1);
    const unsigned int B = E / perBatch;
    const unsigned int rem = E - B * perBatch;  // 2 => symmetric pair appended
    const unsigned int N = B * HW;

    __shared__ int s0[2304];  // row-0 (sources) staging for this block's span
    __shared__ int s1[2304];  // row-1 (targets) staging

    const unsigned int nChunks = (N + 255u) >> 8;  // 256 nodes per chunk
    for (unsigned int chunk = blockIdx.x; chunk < nChunks; chunk += gridDim.x) {
        const unsigned int i0 = chunk << 8;
        const unsigned int iLast = (i0 + 255u < N - 1u) ? (i0 + 255u) : (N - 1u);

        // Contiguous output range owned by this chunk (uniform across block).
        const unsigned int base = node_off(i0, HW, W, H, perBatch);
        const unsigned int span =
            node_off(iLast, HW, W, H, perBatch) + node_cnt(iLast, HW, W, H) - base;

        const unsigned int i = i0 + threadIdx.x;
        if (i <= iLast) {
            const unsigned int b = i / HW;
            const unsigned int p = i - b * HW;
            const unsigned int y = p / W;
            const unsigned int x = p - y * W;
            unsigned int lo = node_off(i, HW, W, H, perBatch) - base;

            const int ii = (int)i;
            s0[lo] = ii; s1[lo] = ii; ++lo;                 // self-loop
            if (x > 0) {
                const int n = ii - 1;
                s0[lo] = ii; s1[lo] = n;  ++lo;
                s0[lo] = n;  s1[lo] = ii; ++lo;
            }
            if (x < W - 1) {
                const int n = ii + 1;
                s0[lo] = ii; s1[lo] = n;  ++lo;
                s0[lo] = n;  s1[lo] = ii; ++lo;
            }
            if (y > 0) {
                const int n = ii - (int)W;
                s0[lo] = ii; s1[lo] = n;  ++lo;
                s0[lo] = n;  s1[lo] = ii; ++lo;
            }
            if (y < H - 1) {
                const int n = ii + (int)W;
                s0[lo] = ii; s1[lo] = n;  ++lo;
                s0[lo] = n;  s1[lo] = ii; ++lo;
            }
        }
        __syncthreads();

        // Coalesced flush: consecutive lanes -> consecutive ints.
        for (unsigned int t = threadIdx.x; t < span; t += 256u) {
            out[base + t]     = s0[t];
            out[E + base + t] = s1[t];
        }

        // Last-node symmetric pair, appended at the very end of the edge list.
        // 2*cx - x == (W-1) - x exactly (cx=(W-1)/2), same for y. These slots
        // (E-2, E-1) lie past every chunk's span (main edges end at E-2), so
        // no overlap with the staged flush.
        if (rem == 2u && i == N - 1u) {
            const unsigned int b = i / HW;
            const unsigned int p = i - b * HW;
            const unsigned int y = p / W;
            const unsigned int x = p - y * W;
            const int ii = (int)i;
            const int sx = (int)(W - 1u - x);
            const int sy = (int)(H - 1u - y);
            const int sidx = (int)(b * HW) + sy * (int)W + sx;
            out[E - 2u]      = ii;   out[E - 1u]      = sidx;
            out[2u * E - 2u] = sidx; out[2u * E - 1u] = ii;
        }

        __syncthreads();  // LDS reuse guard for the next grid-stride chunk
    }
}

extern "C" void kernel_launch(void* const* d_in, const int* in_sizes, int n_in,
                              void* d_out, int out_size, void* d_ws, size_t ws_size,
                              hipStream_t stream) {
    // d_in[0] = node_features (unused — only its size matters, and only on device)
    // d_in[1] = height (device int scalar), d_in[2] = width (device int scalar)
    const int* hptr = (const int*)d_in[1];
    const int* wptr = (const int*)d_in[2];
    int* out = (int*)d_out;

    // N is only derivable on-device (H,W live in device memory), so the kernel
    // grid-strides over 256-node chunks. 1024 blocks covers the benchmark
    // shape (784 chunks) in a single stride iteration.
    const int threads = 256;
    const int blocks = 1024;
    EdgeIndexGenerator_12524124635757_kernel<<<blocks, threads, 0, stream>>>(
        hptr, wptr, out, (unsigned int)out_size);
}